// Round 10
// baseline (216.665 us; speedup 1.0000x reference)
//
#include <hip/hip_runtime.h>

constexpr int IMW  = 96;
constexpr int NPIX = 9216;
constexpr int NM   = 35;     // Fourier modes (truncation err < 1e-8)
constexpr int NPK  = 18;     // 72 channels = 18 float4 packs (71 real + 1 zero)
constexpr int NPART= 6;      // V-stage partial groups (3 packs each)

constexpr float LCLIP = 18.420681f;               // -log(1e-8)

__device__ __forceinline__ float sigq(float delta){ return 1.f/(1.f+__expf(delta)); }

// ---------------- init: Fourier basis tables + spatial tap tables ----------------
// channels: c0 = DC; c1..35 = cos_m; c36..70 = sin_m; c71 = zero.
// Bsplat_c = A_c * basis (A folds coeff a_m AND compat 10); Bslice_c = basis.
// taps: T[i] = exp(-(i-96)^2 / (2*sxy^2 related)) for i in [1,191], T[0]=T[192]=0.
__global__ __launch_bounds__(256) void k_init(const float* __restrict__ img,
        float* __restrict__ Bsplat, float* __restrict__ Bslice,
        float* __restrict__ T50, float* __restrict__ T3){
    int j = blockIdx.x*256 + threadIdx.x;
    if (blockIdx.x == 0 && threadIdx.x < 193){
        int i = threadIdx.x;
        float v50 = 0.f, v3 = 0.f;
        if (i >= 1 && i <= 191){
            float d = (float)(i - 96);            // d in [-95, 95]
            v50 = __expf(-d*d*(1.f/5000.f));      // bilateral spatial, sxy=50
            v3  = __expf(-d*d*(1.f/18.f));        // gaussian spatial, sxy=3
        }
        T50[i] = v50; T3[i] = v3;
    }
    if (j >= NPIX) return;
    float f  = img[j];
    float th = f * 0.0122718463f;                  // 2*pi/512
    // DC channel
    Bsplat[(0*NPIX + j)*4 + 0] = 0.6923648f;       // 10*sqrt(400*pi)/512
    Bslice[(0*NPIX + j)*4 + 0] = 1.f;
    for (int m = 1; m <= NM; ++m){
        float s, c;
        sincosf((float)m * th, &s, &c);            // libm: accurate reduction
        float A = 1.3847296f * __expf(-0.0150598f * (float)(m*m));
        int c1 = m, c2 = NM + m;                   // cos -> 1..35, sin -> 36..70
        Bsplat[((c1>>2)*NPIX + j)*4 + (c1&3)] = A * c;
        Bslice[((c1>>2)*NPIX + j)*4 + (c1&3)] = c;
        Bsplat[((c2>>2)*NPIX + j)*4 + (c2&3)] = A * s;
        Bslice[((c2>>2)*NPIX + j)*4 + (c2&3)] = s;
    }
    Bsplat[(17*NPIX + j)*4 + 3] = 0.f;             // pad channel 71
    Bslice[(17*NPIX + j)*4 + 3] = 0.f;
}

// ---------------- K_H: q-update + splat + horizontal conv ----------------
// MODE 0: q0 from mask; blockIdx.y in [0,36): y>=18 -> splat ones (for ksum pipeline)
// MODE 1: reconstruct q from msgpart; reduce ksumpart and persist ksum
// MODE 2: reconstruct q; read persisted ksum
// block = rowquad B (rows 4B..4B+3) x one pack. R=2 outputs/thread (taps wave-uniform).
template<int MODE>
__global__ __launch_bounds__(192) void k_H(const float* __restrict__ img,
        const int* __restrict__ mask,
        const float* __restrict__ msgpart, const float* __restrict__ ksumpart,
        float* __restrict__ ksum, const float* __restrict__ qprev, float* __restrict__ qcur,
        const float4* __restrict__ Bsplat,
        float4* __restrict__ SH, float4* __restrict__ SHk,
        float* __restrict__ SHg3, float* __restrict__ SHg3k,
        const float* __restrict__ T50, const float* __restrict__ T3){
    __shared__ float4 P[4][288];       // zero-padded splat rows
    __shared__ float  qpad[4][288];    // zero-padded q rows (for g3 channel)
    const int t  = threadIdx.x;
    const int B  = blockIdx.x;
    const int g0 = blockIdx.y;
    const bool ones = (MODE == 0) && (g0 >= NPK);
    const int pack  = ones ? g0 - NPK : g0;

    for (int k = t; k < 4*288; k += 192){ P[k/288][k%288] = make_float4(0.f,0.f,0.f,0.f); qpad[k/288][k%288] = 0.f; }
    __syncthreads();

    // q for this block's 4 rows (2 px per thread)
    for (int l = t; l < 4*IMW; l += 192){
        int r = l / IMW, xx = l % IMW;
        int y = 4*B + r, j = y*IMW + xx;
        float q;
        if (ones) q = 1.f;
        else if (MODE == 0){
            q = (mask[j]==0) ? sigq(LCLIP) : sigq(-LCLIP);
        } else {
            float m = 0.f;
            #pragma unroll
            for (int p = 0; p < NPART; ++p) m += msgpart[p*NPIX + xx*IMW + y];
            float kk;
            if (MODE == 1){
                kk = 0.f;
                #pragma unroll
                for (int p = 0; p < NPART; ++p) kk += ksumpart[p*NPIX + xx*IMW + y];
                kk -= 13.f;                          // remove diagonal from colsum
                if (g0 == 0) ksum[j] = kk;           // persist (iteration-invariant)
            } else {
                kk = ksum[j];
            }
            float duv = (mask[j]==0) ? LCLIP : -LCLIP;
            float delta = duv + kk - 2.f*(m - 13.f*qprev[j]);   // diag removal
            q = sigq(delta);
        }
        if (!ones && g0 == 0) qcur[j] = q;           // designated writer
        qpad[r][xx + 96] = q;
    }
    __syncthreads();
    // splat: P = q * Bsplat (this block's pack)
    for (int l = t; l < 4*IMW; l += 192){
        int r = l / IMW, xx = l % IMW;
        int j = (4*B + r)*IMW + xx;
        float4 bv = Bsplat[pack*NPIX + j];
        float  qv = qpad[r][xx + 96];
        P[r][xx + 96] = make_float4(qv*bv.x, qv*bv.y, qv*bv.z, qv*bv.w);
    }
    __syncthreads();

    // H conv: thread -> (row r, outputs x0, x0+1); tap index wave-uniform (s_load)
    const int r  = t / 48;
    const int xg = t % 48;
    const int x0 = 2*xg;
    float4 a0 = make_float4(0.f,0.f,0.f,0.f), a1 = a0;
    float g30 = 0.f, g31 = 0.f;
    #pragma unroll 4
    for (int k = 0; k < 192; ++k){
        float4 v = P[r][x0 + k + 1];
        float w0 = T50[191 - k];
        float w1 = T50[192 - k];
        a0.x = fmaf(w0, v.x, a0.x); a0.y = fmaf(w0, v.y, a0.y);
        a0.z = fmaf(w0, v.z, a0.z); a0.w = fmaf(w0, v.w, a0.w);
        a1.x = fmaf(w1, v.x, a1.x); a1.y = fmaf(w1, v.y, a1.y);
        a1.z = fmaf(w1, v.z, a1.z); a1.w = fmaf(w1, v.w, a1.w);
        if (pack == 0){
            float qv = qpad[r][x0 + k + 1];
            g30 = fmaf(T3[191 - k], qv, g30);
            g31 = fmaf(T3[192 - k], qv, g31);
        }
    }
    const int y = 4*B + r;
    float4* dst = ones ? SHk : SH;
    dst[pack*NPIX + y*IMW + x0]     = a0;
    dst[pack*NPIX + y*IMW + x0 + 1] = a1;
    if (pack == 0){
        float* dg = ones ? SHg3k : SHg3;
        dg[y*IMW + x0] = g30; dg[y*IMW + x0 + 1] = g31;
    }
}

// ---------------- K_V: vertical conv + slice -> per-part message partials ----------------
// block = colpair x part (3 packs). blockIdx.y >= NPART -> ones pipeline (ksum).
__global__ __launch_bounds__(192) void k_V(
        const float4* __restrict__ SH, const float4* __restrict__ SHk,
        const float* __restrict__ SHg3, const float* __restrict__ SHg3k,
        const float4* __restrict__ Bslice,
        float* __restrict__ msgpart, float* __restrict__ ksumpart,
        const float* __restrict__ T50, const float* __restrict__ T3){
    __shared__ float t50[193], t3[193];
    const int t = threadIdx.x;
    if (t < 193){ t50[t] = T50[t]; t3[t] = T3[t]; }
    const int c2 = blockIdx.x, g0 = blockIdx.y;
    const bool ones = g0 >= NPART;
    const int g  = ones ? g0 - NPART : g0;
    const int cc = t / 96, y = t % 96;
    const int col = 2*c2 + cc;
    __syncthreads();

    const float4* SB = ones ? SHk : SH;
    double msg = 0.0;
    #pragma unroll
    for (int pp = 0; pp < 3; ++pp){
        int pk = 3*g + pp;
        const float4* src = SB + pk*NPIX + col;
        float4 ac[4];
        #pragma unroll
        for (int s = 0; s < 4; ++s) ac[s] = make_float4(0.f,0.f,0.f,0.f);
        #pragma unroll
        for (int s = 0; s < 4; ++s){          // 4-way split accumulators (error control)
            #pragma unroll 8
            for (int u = 0; u < 24; ++u){
                int yp = s*24 + u;
                float w = t50[y - yp + 96];
                float4 v = src[yp*IMW];
                ac[s].x = fmaf(w, v.x, ac[s].x); ac[s].y = fmaf(w, v.y, ac[s].y);
                ac[s].z = fmaf(w, v.z, ac[s].z); ac[s].w = fmaf(w, v.w, ac[s].w);
            }
        }
        double sx = (double)ac[0].x + (double)ac[1].x + (double)ac[2].x + (double)ac[3].x;
        double sy = (double)ac[0].y + (double)ac[1].y + (double)ac[2].y + (double)ac[3].y;
        double sz = (double)ac[0].z + (double)ac[1].z + (double)ac[2].z + (double)ac[3].z;
        double sw = (double)ac[0].w + (double)ac[1].w + (double)ac[2].w + (double)ac[3].w;
        float4 bs = Bslice[pk*NPIX + y*IMW + col];
        msg += sx*(double)bs.x + sy*(double)bs.y + sz*(double)bs.z + sw*(double)bs.w;
    }
    if (g == 0){                               // sxy=3 gaussian channel (compat 3)
        const float* sg = (ones ? SHg3k : SHg3) + col;
        float ag = 0.f;
        for (int yp = 0; yp < 96; ++yp)
            ag = fmaf(t3[y - yp + 96], sg[yp*IMW], ag);
        msg += 3.0 * (double)ag;
    }
    (ones ? ksumpart : msgpart)[g*NPIX + col*IMW + y] = (float)msg;
}

// ---------------- final: 5th update + argmax ----------------
__global__ __launch_bounds__(256) void k_F(const int* __restrict__ mask,
        const float* __restrict__ msgpart, const float* __restrict__ ksum,
        const float* __restrict__ qprev, float* __restrict__ out){
    int j = blockIdx.x*256 + threadIdx.x;
    int xx = j % IMW, y = j / IMW;
    float m = 0.f;
    #pragma unroll
    for (int p = 0; p < NPART; ++p) m += msgpart[p*NPIX + xx*IMW + y];
    float duv = (mask[j]==0) ? LCLIP : -LCLIP;
    float delta = duv + ksum[j] - 2.f*(m - 13.f*qprev[j]);
    out[j] = (delta > 0.f) ? 1.f : 0.f;        // argmax; tie -> label 0
}

extern "C" void kernel_launch(void* const* d_in, const int* in_sizes, int n_in,
                              void* d_out, int out_size, void* d_ws, size_t ws_size,
                              hipStream_t stream){
    const float* img  = (const float*)d_in[0];
    const int*   mask = (const int*)d_in[1];
    float* out = (float*)d_out;
    float* ws  = (float*)d_ws;

    constexpr size_t SZB = (size_t)NPK*NPIX*4;     // pack-table floats
    float* Bsplat = ws;
    float* Bslice = Bsplat + SZB;
    float* SH     = Bslice + SZB;
    float* SHk    = SH     + SZB;
    float* SHg3   = SHk    + SZB;
    float* SHg3k  = SHg3   + NPIX;
    float* msgp   = SHg3k  + NPIX;                 // [6][NPIX] col-major px
    float* ksump  = msgp   + (size_t)NPART*NPIX;
    float* qA     = ksump  + (size_t)NPART*NPIX;
    float* qB     = qA + NPIX;
    float* ksum   = qB + NPIX;
    float* T50    = ksum + NPIX;
    float* T3     = T50 + 256;

    k_init<<<dim3(36), dim3(256), 0, stream>>>(img, Bsplat, Bslice, T50, T3);

    // iter 0: q0 from mask; splat q0 AND ones (ksum pipeline)
    k_H<0><<<dim3(24,36), dim3(192), 0, stream>>>(img, mask, msgp, ksump, ksum, qA, qA,
            (const float4*)Bsplat, (float4*)SH, (float4*)SHk, SHg3, SHg3k, T50, T3);
    k_V<<<dim3(48,12), dim3(192), 0, stream>>>((const float4*)SH, (const float4*)SHk,
            SHg3, SHg3k, (const float4*)Bslice, msgp, ksump, T50, T3);
    // iter 1: reconstruct q1, persist ksum
    k_H<1><<<dim3(24,18), dim3(192), 0, stream>>>(img, mask, msgp, ksump, ksum, qA, qB,
            (const float4*)Bsplat, (float4*)SH, (float4*)SHk, SHg3, SHg3k, T50, T3);
    k_V<<<dim3(48,6), dim3(192), 0, stream>>>((const float4*)SH, (const float4*)SHk,
            SHg3, SHg3k, (const float4*)Bslice, msgp, ksump, T50, T3);
    // iters 2..4
    k_H<2><<<dim3(24,18), dim3(192), 0, stream>>>(img, mask, msgp, ksump, ksum, qB, qA,
            (const float4*)Bsplat, (float4*)SH, (float4*)SHk, SHg3, SHg3k, T50, T3);
    k_V<<<dim3(48,6), dim3(192), 0, stream>>>((const float4*)SH, (const float4*)SHk,
            SHg3, SHg3k, (const float4*)Bslice, msgp, ksump, T50, T3);
    k_H<2><<<dim3(24,18), dim3(192), 0, stream>>>(img, mask, msgp, ksump, ksum, qA, qB,
            (const float4*)Bsplat, (float4*)SH, (float4*)SHk, SHg3, SHg3k, T50, T3);
    k_V<<<dim3(48,6), dim3(192), 0, stream>>>((const float4*)SH, (const float4*)SHk,
            SHg3, SHg3k, (const float4*)Bslice, msgp, ksump, T50, T3);
    k_H<2><<<dim3(24,18), dim3(192), 0, stream>>>(img, mask, msgp, ksump, ksum, qB, qA,
            (const float4*)Bsplat, (float4*)SH, (float4*)SHk, SHg3, SHg3k, T50, T3);
    k_V<<<dim3(48,6), dim3(192), 0, stream>>>((const float4*)SH, (const float4*)SHk,
            SHg3, SHg3k, (const float4*)Bslice, msgp, ksump, T50, T3);
    // iter 5: final update + argmax (q4 = qA)
    k_F<<<dim3(36), dim3(256), 0, stream>>>(mask, msgp, ksum, qA, out);
}